// Round 4
// baseline (812.717 us; speedup 1.0000x reference)
//
#include <hip/hip_runtime.h>

// TensorTrain: BS=16384, N_CH=8, H=256, RANK=16, N_AGGR=4, T=64, R=272 (r<256 used)
//
// Round-4 design (r-major orientation):
//  - block = 1024 thr = 16 waves = 4 aggregators (a) x 4 K-quarters (kq), 64 samples.
//  - GEMM computes D[r][sample]: A-operand = U fragments (global L2 ring),
//    B-operand = nh fragments (LDS-staged bf16). Scan weight carry[sample][t]
//    is then a same-address-broadcast LDS read (no shuffles at all).
//  - Cross-kq reduction: ds_add_f32 into a 3-buffer rotating exchange
//    (read cur / add nxt / zero cur-1) -> race-free with 1 barrier/channel.
//  - Epilogue: zero-padded 16x16x32 MFMA, A-frags read from the LDS carry.

#define N_CH 8

typedef __bf16 bf16x8 __attribute__((ext_vector_type(8)));
typedef float  f32x4  __attribute__((ext_vector_type(4)));

union BF8 { bf16x8 v; unsigned short s[8]; uint4 q; };

static __device__ __forceinline__ unsigned short f2bf(float x) {
  union { float f; unsigned u; } t; t.f = x;
  return (unsigned short)((t.u + 0x7FFFu + ((t.u >> 16) & 1u)) >> 16); // RNE
}
static __device__ __forceinline__ unsigned pk2(float a, float b) {
  return (unsigned)f2bf(a) | ((unsigned)f2bf(b) << 16);
}

// ---- prep: U[ca][h][r<256] f32 -> bf16 MFMA-fragment order, LDS-tiled transpose.
// Chunk (ca,t,ks) = 1KB: [lane][j]: r = 16t + (lane&15), h = 32ks + 8*(lane>>4) + j.
__global__ __launch_bounds__(256) void prep_U(const float* __restrict__ U,
                                              unsigned* __restrict__ Ubf) {
  __shared__ float tile[32][257];
  const int ca = blockIdx.x >> 3;
  const int ks = blockIdx.x & 7;
  const int tid = threadIdx.x;
#pragma unroll 4
  for (int i = 0; i < 32; ++i)
    tile[i][tid] = U[((size_t)(ca * 256 + ks * 32 + i)) * 272 + tid];
  __syncthreads();
  const int lane = tid & 63, tq = tid >> 6;
  const int rl = lane & 15, q = lane >> 4;
#pragma unroll
  for (int tt = 0; tt < 4; ++tt) {
    const int t = tt * 4 + tq;
    float v[8];
#pragma unroll
    for (int j = 0; j < 8; ++j) v[j] = tile[q * 8 + j][t * 16 + rl];
    uint4 o;
    o.x = pk2(v[0], v[1]); o.y = pk2(v[2], v[3]);
    o.z = pk2(v[4], v[5]); o.w = pk2(v[6], v[7]);
    *(uint4*)(Ubf + ((((size_t)ca * 16 + t) * 8 + ks) << 8) + lane * 4) = o;
  }
}

// Dynamic LDS: A bf16 double-buffer, 64 rows x 528 B each.
#define LDS_A0 0
#define LDS_A1 33792
// Static LDS: 3 exchange buffers, [buf][a][r][sample]: buf*4352 + a*1088 + r*68 + s (floats)
#define EXF 4352

__global__ __launch_bounds__(1024) void tt_main(
    const float* __restrict__ nh,            // (16384, 8, 256)
    const float* __restrict__ ty,            // (16384, 64)
    const unsigned short* __restrict__ Ubf,  // frag-ordered bf16 U (4 MB)
    const float* __restrict__ bB,            // (8, 4, 1, 272)
    const float* __restrict__ Ut,            // (4, 64, 16)
    const float* __restrict__ bt,            // (4, 1, 16)
    const float* __restrict__ Uo,            // (4, 16, 256)
    const float* __restrict__ bo,            // (4, 1, 256)
    float* __restrict__ out)                 // (16384, 1024)
{
  extern __shared__ char smem[];
  __shared__ __align__(16) float EXs[3 * EXF];

  const int tid  = threadIdx.x;
  const int lane = tid & 63;
  const int w    = tid >> 6;
  const int a    = w & 3;       // aggregator
  const int kq   = w >> 2;      // K-quarter (64 of 256)
  const int b0   = blockIdx.x * 64;
  const int rl   = lane & 15;
  const int q    = lane >> 4;

  const float4 f0 = make_float4(0.f, 0.f, 0.f, 0.f);

  // zero all 3 exchange buffers (13056 floats)
  for (int i = tid; i < 3264; i += 1024) ((float4*)EXs)[i] = f0;

  // stage A (nh bf16) for channel 0
  {
    const int row = tid >> 4, kb = (tid & 15) * 16;
    const float* s = nh + ((size_t)(b0 + row) * N_CH + 0) * 256 + kb;
    float4 x0 = ((const float4*)s)[0], x1 = ((const float4*)s)[1];
    float4 x2 = ((const float4*)s)[2], x3 = ((const float4*)s)[3];
    uint4 o0, o1;
    o0.x = pk2(x0.x, x0.y); o0.y = pk2(x0.z, x0.w);
    o0.z = pk2(x1.x, x1.y); o0.w = pk2(x1.z, x1.w);
    o1.x = pk2(x2.x, x2.y); o1.y = pk2(x2.z, x2.w);
    o1.z = pk2(x3.x, x3.y); o1.w = pk2(x3.z, x3.w);
    *(uint4*)(smem + LDS_A0 + row * 528 + kb * 2)      = o0;
    *(uint4*)(smem + LDS_A0 + row * 528 + kb * 2 + 16) = o1;
  }
  __syncthreads();   // zeroes + A0 visible

  // ---- carry init into EX[0]: rank_ris0[r][s] = (U_type[a])^T ty^T + b_type
  if (kq == 0) {
    BF8 utf[2];  // A-operand: A[r = lane&15][k(t-dim) = q*8+j]
#pragma unroll
    for (int ks2 = 0; ks2 < 2; ++ks2)
#pragma unroll
      for (int j = 0; j < 8; ++j)
        utf[ks2].s[j] = f2bf(Ut[a * 1024 + (ks2 * 32 + q * 8 + j) * 16 + rl]);
    const float4 bt4 = *(const float4*)(bt + a * 16 + q * 4);  // bias per r-row
#pragma unroll
    for (int nt = 0; nt < 4; ++nt) {
      f32x4 acc = { bt4.x, bt4.y, bt4.z, bt4.w };
#pragma unroll
      for (int ks2 = 0; ks2 < 2; ++ks2) {
        const float* s = ty + (size_t)(b0 + nt * 16 + rl) * 64 + ks2 * 32 + q * 8;
        float4 y0 = ((const float4*)s)[0], y1 = ((const float4*)s)[1];
        BF8 bf;  // B-operand: B[sample = lane&15][k]
        bf.s[0] = f2bf(y0.x); bf.s[1] = f2bf(y0.y); bf.s[2] = f2bf(y0.z); bf.s[3] = f2bf(y0.w);
        bf.s[4] = f2bf(y1.x); bf.s[5] = f2bf(y1.y); bf.s[6] = f2bf(y1.z); bf.s[7] = f2bf(y1.w);
        acc = __builtin_amdgcn_mfma_f32_16x16x32_bf16(utf[ks2].v, bf.v, acc, 0, 0, 0);
      }
#pragma unroll
      for (int i = 0; i < 4; ++i)
        atomicAdd(&EXs[a * 1088 + (q * 4 + i) * 68 + nt * 16 + rl], acc[i]);
    }
  }
  __syncthreads();   // init carry visible

  float4 sg0, sg1, sg2, sg3;   // A(c+1) staging regs, loaded at t==14

#pragma unroll 1
  for (int c = 0; c < N_CH; ++c) {
    const int cur = c % 3, nxt = (c + 1) % 3, zro = (c + 2) % 3;
    const float* exC = EXs + cur * EXF + a * 1088;
    float*       exN = EXs + nxt * EXF + a * 1088;
    const int aCur = (c & 1) ? LDS_A1 : LDS_A0;
    const int aNxt = (c & 1) ? LDS_A0 : LDS_A1;

    // nh B-fragments: B[sample][k], this wave's K-quarter (32 VGPR)
    BF8 Nf[4][2];
#pragma unroll
    for (int nt = 0; nt < 4; ++nt)
#pragma unroll
      for (int s2 = 0; s2 < 2; ++s2)
        Nf[nt][s2].q = *(const uint4*)(smem + aCur + (nt * 16 + rl) * 528 +
                                       (2 * kq + s2) * 64 + q * 16);

    // zero EX[zro] = channel (c-1)'s read buffer (readers done before last barrier);
    // it receives channel (c+1)'s adds, which start only after this channel's barrier.
    for (int i = tid; i < 1088; i += 1024) ((float4*)(EXs + zro * EXF))[i] = f0;

    // U A-operand ring: preload tiles 0,1 from L2 (+ per-r bias for kq==0)
    const unsigned short* Uc = Ubf + (size_t)(c * 4 + a) * 65536;
    const float* bBp = bB + (c * 4 + a) * 272;
    uint4 Ur[2][2]; float4 bb[2];
#pragma unroll
    for (int h2 = 0; h2 < 2; ++h2) {
      const unsigned short* up = Uc + h2 * 4096 + 2 * kq * 512 + lane * 8;
      Ur[h2][0] = *(const uint4*)up;
      Ur[h2][1] = *(const uint4*)(up + 512);
      bb[h2] = (kq == 0) ? *(const float4*)(bBp + h2 * 16 + q * 4) : f0;
    }

    f32x4 partial[4];
#pragma unroll
    for (int nt = 0; nt < 4; ++nt) partial[nt] = { 0.f, 0.f, 0.f, 0.f };

#pragma unroll 1
    for (int tp = 0; tp < 8; ++tp) {
#pragma unroll
      for (int half = 0; half < 2; ++half) {
        const int t = tp * 2 + half;
        // scan weights: carry[sample = nt*16+rl][t] — broadcast LDS reads
        const float* cvp = exC + t * 68 + rl;
        float cv0 = cvp[0], cv1 = cvp[16], cv2 = cvp[32], cv3 = cvp[48];
        BF8 ua0, ua1; ua0.q = Ur[half][0]; ua1.q = Ur[half][1];
        const float4 bs = bb[half];
        f32x4 acc[4];
#pragma unroll
        for (int nt = 0; nt < 4; ++nt) acc[nt] = { bs.x, bs.y, bs.z, bs.w };
#pragma unroll
        for (int nt = 0; nt < 4; ++nt)
          acc[nt] = __builtin_amdgcn_mfma_f32_16x16x32_bf16(ua0.v, Nf[nt][0].v, acc[nt], 0, 0, 0);
#pragma unroll
        for (int nt = 0; nt < 4; ++nt)
          acc[nt] = __builtin_amdgcn_mfma_f32_16x16x32_bf16(ua1.v, Nf[nt][1].v, acc[nt], 0, 0, 0);
        if (t < 14) {  // ring prefetch t+2 into the just-consumed slot
          const unsigned short* up = Uc + (size_t)(t + 2) * 4096 + 2 * kq * 512 + lane * 8;
          Ur[half][0] = *(const uint4*)up;
          Ur[half][1] = *(const uint4*)(up + 512);
          if (kq == 0) bb[half] = *(const float4*)(bBp + (t + 2) * 16 + q * 4);
        }
        if (t == 14 && c < 7) {  // A(c+1) staging loads
          const int row = tid >> 4, kb = (tid & 15) * 16;
          const float* s = nh + ((size_t)(b0 + row) * N_CH + (c + 1)) * 256 + kb;
          sg0 = ((const float4*)s)[0]; sg1 = ((const float4*)s)[1];
          sg2 = ((const float4*)s)[2]; sg3 = ((const float4*)s)[3];
        }
        // fused scan step (t=15 also adds the b_rank row: weight +1)
        const float extra = (t == 15) ? 1.0f : 0.0f;
        const float cva[4] = { cv0 + extra, cv1 + extra, cv2 + extra, cv3 + extra };
#pragma unroll
        for (int nt = 0; nt < 4; ++nt)
#pragma unroll
          for (int i = 0; i < 4; ++i)
            partial[nt][i] += cva[nt] * acc[nt][i];
      }
    }

    // write staged A(c+1) (its buffer's readers finished before the last barrier)
    if (c < 7) {
      const int row = tid >> 4, kb = (tid & 15) * 16;
      uint4 o0, o1;
      o0.x = pk2(sg0.x, sg0.y); o0.y = pk2(sg0.z, sg0.w);
      o0.z = pk2(sg1.x, sg1.y); o0.w = pk2(sg1.z, sg1.w);
      o1.x = pk2(sg2.x, sg2.y); o1.y = pk2(sg2.z, sg2.w);
      o1.z = pk2(sg3.x, sg3.y); o1.w = pk2(sg3.z, sg3.w);
      *(uint4*)(smem + aNxt + row * 528 + kb * 2)      = o0;
      *(uint4*)(smem + aNxt + row * 528 + kb * 2 + 16) = o1;
    }

    // cross-kq reduction into EX[nxt]
#pragma unroll
    for (int nt = 0; nt < 4; ++nt)
#pragma unroll
      for (int i = 0; i < 4; ++i)
        atomicAdd(&exN[(q * 4 + i) * 68 + nt * 16 + rl], partial[nt][i]);
    __syncthreads();
  }

  // ---- epilogue: out[s][a*256+h] = rank_ris[s][:] @ Uo[a] + bo[a], zero-padded MFMA.
  // Final carry is in EX[(7+1)%3 == 2], layout [a][r][sample].
  const float* exF = EXs + 2 * EXF + a * 1088;
  BF8 Ae[4];  // A[m = sample][k = r], zero for k>=16
#pragma unroll
  for (int mt = 0; mt < 4; ++mt) {
    uint4 zq; zq.x = zq.y = zq.z = zq.w = 0u;
    Ae[mt].q = zq;
    if (q < 2) {
#pragma unroll
      for (int j = 0; j < 8; ++j)
        Ae[mt].s[j] = f2bf(exF[(q * 8 + j) * 68 + mt * 16 + rl]);
    }
  }
#pragma unroll
  for (int nt = 0; nt < 4; ++nt) {
    const int hc = (4 * kq + nt) * 16;   // h-column base for this wave
    BF8 Be;  // B[n = h-col][k = r], zero for k>=16
#pragma unroll
    for (int j = 0; j < 8; ++j) {
      float x = 0.f;
      if (q < 2) x = Uo[a * 4096 + (q * 8 + j) * 256 + hc + rl];
      Be.s[j] = (q < 2) ? f2bf(x) : (unsigned short)0;
    }
    const float bv = bo[a * 256 + hc + rl];
#pragma unroll
    for (int mt = 0; mt < 4; ++mt) {
      f32x4 oacc = { bv, bv, bv, bv };
      oacc = __builtin_amdgcn_mfma_f32_16x16x32_bf16(Ae[mt].v, Be.v, oacc, 0, 0, 0);
#pragma unroll
      for (int i = 0; i < 4; ++i)
        out[(size_t)(b0 + mt * 16 + q * 4 + i) * 1024 + a * 256 + hc + rl] = oacc[i];
    }
  }
}

extern "C" void kernel_launch(void* const* d_in, const int* in_sizes, int n_in,
                              void* d_out, int out_size, void* d_ws, size_t ws_size,
                              hipStream_t stream) {
  const float* nh = (const float*)d_in[0];
  const float* ty = (const float*)d_in[1];
  const float* U  = (const float*)d_in[2];
  const float* bB = (const float*)d_in[3];
  const float* Ut = (const float*)d_in[4];
  const float* bt = (const float*)d_in[5];
  const float* Uo = (const float*)d_in[6];
  const float* bo = (const float*)d_in[7];
  float* out = (float*)d_out;

  unsigned* Ubf32 = (unsigned*)d_ws;  // 4 MB frag-ordered bf16 U

  prep_U<<<256, 256, 0, stream>>>(U, Ubf32);

  (void)hipFuncSetAttribute((const void*)tt_main,
                            hipFuncAttributeMaxDynamicSharedMemorySize, 67584);
  tt_main<<<256, 1024, 67584, stream>>>(nh, ty, (const unsigned short*)d_ws,
                                        bB, Ut, bt, Uo, bo, out);
}